// Round 1
// baseline (433.947 us; speedup 1.0000x reference)
//
#include <hip/hip_runtime.h>
#include <math.h>

// Problem constants (from reference)
#define Bb 2
#define Ll 2048
#define Dd 512
#define Hh 8
#define DKq 64
#define NBUCK 16
#define KMAX 64
// M = B*L = 4096 rows for all big GEMMs, K=N=512

// ---------------------------------------------------------------------------
// Projection GEMM: X(4096x512) @ W(512x512) + b, output scattered to
// (b, h, l, dk) layout for q/k/v.  BM=128 BN=64 BK=16, 256 thr, 8x4 microtile.
// BN=64 == one head's dk block, so each block writes one head contiguously.
// ---------------------------------------------------------------------------
__global__ __launch_bounds__(256) void proj_kernel(
    const float* __restrict__ Xq, const float* __restrict__ Xk, const float* __restrict__ Xv,
    const float* __restrict__ Wq, const float* __restrict__ Wk, const float* __restrict__ Wv,
    const float* __restrict__ bq, const float* __restrict__ bk, const float* __restrict__ bv,
    float* __restrict__ qb, float* __restrict__ kb, float* __restrict__ vb)
{
  const float *X, *W, *bias; float* dst;
  if (blockIdx.z == 0)      { X=Xq; W=Wq; bias=bq; dst=qb; }
  else if (blockIdx.z == 1) { X=Xk; W=Wk; bias=bk; dst=kb; }
  else                      { X=Xv; W=Wv; bias=bv; dst=vb; }
  __shared__ float As[16][132];   // As[k][m], pad keeps float4 rows 16B aligned
  __shared__ float Bs[16][68];
  const int tid = threadIdx.x;
  const int m0 = blockIdx.y * 128;
  const int head = blockIdx.x;       // N tile == head
  const int n0 = head * 64;
  const int tx = tid & 15, ty = tid >> 4;
  float acc[8][4] = {};
  for (int k0 = 0; k0 < 512; k0 += 16) {
    #pragma unroll
    for (int i = 0; i < 2; i++) {
      int f = tid * 2 + i;              // 0..511 float4s of A tile (128x16)
      int row = f >> 2, colg = (f & 3) << 2;
      float4 a = *(const float4*)&X[(size_t)(m0 + row) * 512 + k0 + colg];
      As[colg+0][row]=a.x; As[colg+1][row]=a.y; As[colg+2][row]=a.z; As[colg+3][row]=a.w;
    }
    {
      int row = tid >> 4, colg = (tid & 15) << 2;   // B tile 16x64
      *(float4*)&Bs[row][colg] = *(const float4*)&W[(size_t)(k0+row)*512 + n0 + colg];
    }
    __syncthreads();
    #pragma unroll
    for (int kk = 0; kk < 16; kk++) {
      float4 a0 = *(const float4*)&As[kk][ty*8];
      float4 a1 = *(const float4*)&As[kk][ty*8+4];
      float4 b0 = *(const float4*)&Bs[kk][tx*4];
      float av[8] = {a0.x,a0.y,a0.z,a0.w,a1.x,a1.y,a1.z,a1.w};
      float bw[4] = {b0.x,b0.y,b0.z,b0.w};
      #pragma unroll
      for (int i=0;i<8;i++)
        #pragma unroll
        for (int j=0;j<4;j++) acc[i][j] += av[i]*bw[j];
    }
    __syncthreads();
  }
  #pragma unroll
  for (int i=0;i<8;i++) {
    int m = m0 + ty*8 + i;
    int b = m >> 11, l = m & 2047;
    float* drow = &dst[(((size_t)b*Hh + head)*Ll + l)*DKq];
    #pragma unroll
    for (int j=0;j<4;j++) {
      int d = tx*4+j;
      drow[d] = acc[i][j] + bias[n0 + d];
    }
  }
}

// ---------------------------------------------------------------------------
// LSH hash: one wave per (q or k) row.  bucket = floor(sum_{d:x_d>0} r_d /8) mod 16
// ---------------------------------------------------------------------------
__global__ __launch_bounds__(256) void hash_kernel(
    const float* __restrict__ qb, const float* __restrict__ kb,
    const float* __restrict__ rv, int* __restrict__ qhash, int* __restrict__ khash)
{
  int gwave = (blockIdx.x * blockDim.x + threadIdx.x) >> 6;
  int lane = threadIdx.x & 63;
  const int NR = Bb * Hh * Ll;             // 32768 rows each for q and k
  if (gwave >= 2 * NR) return;
  int isK = gwave >= NR;
  int row = isK ? gwave - NR : gwave;      // row = (b*H+h)*L + l
  int h = (row >> 11) & 7;
  const float* src = isK ? kb : qb;
  float x = src[(size_t)row * DKq + lane];
  float r = rv[h * DKq + lane];
  float v = (x > 0.0f) ? r : 0.0f;
  #pragma unroll
  for (int off = 32; off; off >>= 1) v += __shfl_xor(v, off);
  if (lane == 0) {
    float fb = floorf(v * 0.125f);         // /8 exact (pow2)
    int ib = (int)fb;
    int bucket = ib & 15;                  // two's-complement & == mod 16 >=0
    (isK ? khash : qhash)[row] = bucket;
  }
}

// ---------------------------------------------------------------------------
// First <=64 ascending key indices per (b,h,bucket): one wave, ballot scan.
// ---------------------------------------------------------------------------
__global__ __launch_bounds__(64) void kcand_kernel(
    const int* __restrict__ khash, int* __restrict__ kcand, int* __restrict__ kcount)
{
  int bh = blockIdx.x >> 4;
  int bucket = blockIdx.x & 15;
  int lane = threadIdx.x;
  const int* kh = &khash[bh * Ll];
  int* cl = &kcand[(size_t)blockIdx.x * KMAX];
  int total = 0;
  for (int c0 = 0; c0 < Ll && total < KMAX; c0 += 64) {
    int hv = kh[c0 + lane];
    unsigned long long m = __ballot(hv == bucket);
    int pre = __popcll(m & ((1ULL << lane) - 1ULL));
    if (hv == bucket && total + pre < KMAX) cl[total + pre] = c0 + lane;
    total += __popcll(m);
  }
  if (lane == 0) kcount[blockIdx.x] = total < KMAX ? total : KMAX;
}

// ---------------------------------------------------------------------------
// Group queries by bucket per (b,h): counting sort (order in bucket irrelevant).
// ---------------------------------------------------------------------------
__global__ __launch_bounds__(256) void qlist_kernel(
    const int* __restrict__ qhash, int* __restrict__ qoff, int* __restrict__ qlist)
{
  int bh = blockIdx.x;
  __shared__ int cnt[NBUCK], cur[NBUCK], off[NBUCK + 1];
  if (threadIdx.x < NBUCK) cnt[threadIdx.x] = 0;
  __syncthreads();
  const int* qh = &qhash[bh * Ll];
  for (int l = threadIdx.x; l < Ll; l += 256) atomicAdd(&cnt[qh[l]], 1);
  __syncthreads();
  if (threadIdx.x == 0) {
    int s = 0;
    for (int i = 0; i < NBUCK; i++) { off[i] = s; cur[i] = s; s += cnt[i]; }
    off[NBUCK] = s;
  }
  __syncthreads();
  if (threadIdx.x < NBUCK + 1) qoff[bh * (NBUCK + 1) + threadIdx.x] = off[threadIdx.x];
  for (int l = threadIdx.x; l < Ll; l += 256) {
    int p = atomicAdd(&cur[qh[l]], 1);
    qlist[bh * Ll + p] = l;
  }
}

// ---------------------------------------------------------------------------
// Attention: block = (b,h,bucket,chunk-of-64-queries).  Stage <=64 cand K/V
// rows + 64 q rows in LDS; each of 4 waves does one query at a time:
// lane==candidate for sim/softmax, lane==dim for ctx.
// ---------------------------------------------------------------------------
__global__ __launch_bounds__(256) void attn_kernel(
    const float* __restrict__ qb, const float* __restrict__ kb, const float* __restrict__ vb,
    const int* __restrict__ qoff, const int* __restrict__ qlist,
    const int* __restrict__ kcand, const int* __restrict__ kcount,
    float* __restrict__ ctx)
{
  int gb = blockIdx.x;
  int chunk = gb & 31;
  int bucket = (gb >> 5) & 15;
  int bh = gb >> 9;
  int o0 = qoff[bh * 17 + bucket], o1 = qoff[bh * 17 + bucket + 1];
  int nq = o1 - o0 - chunk * 64;
  if (nq <= 0) return;
  if (nq > 64) nq = 64;
  int cnt = kcount[bh * 16 + bucket];
  if (cnt == 0) return;   // ref would be NaN; assumed absent in data
  __shared__ float ks[64][65], vs[64][65], qs[64][65];
  __shared__ int cidx[64], qidx[64];
  int tid = threadIdx.x;
  if (tid < 64) {
    cidx[tid] = (tid < cnt) ? kcand[((size_t)bh * 16 + bucket) * KMAX + tid] : 0;
    qidx[tid] = (tid < nq) ? qlist[bh * Ll + o0 + chunk * 64 + tid] : 0;
  }
  __syncthreads();
  const float* kbh = &kb[(size_t)bh * Ll * DKq];
  const float* vbh = &vb[(size_t)bh * Ll * DKq];
  const float* qbh = &qb[(size_t)bh * Ll * DKq];
  for (int idx = tid; idx < 64 * 64; idx += 256) {
    int r = idx >> 6, d = idx & 63;
    if (r < cnt) {
      ks[r][d] = kbh[(size_t)cidx[r] * DKq + d];
      vs[r][d] = vbh[(size_t)cidx[r] * DKq + d];
    }
    if (r < nq) qs[r][d] = qbh[(size_t)qidx[r] * DKq + d];
  }
  __syncthreads();
  int wave = tid >> 6, lane = tid & 63;
  for (int qi = wave; qi < nq; qi += 4) {
    float s = -INFINITY;
    if (lane < cnt) {
      float acc = 0.f;
      #pragma unroll
      for (int d = 0; d < 64; d++) acc += qs[qi][d] * ks[lane][d];
      s = acc * 0.125f;   // / sqrt(64)
    }
    float m = s;
    #pragma unroll
    for (int off = 32; off; off >>= 1) m = fmaxf(m, __shfl_xor(m, off));
    float e = expf(s - m);           // lanes >= cnt: exp(-inf)=0
    float sum = e;
    #pragma unroll
    for (int off = 32; off; off >>= 1) sum += __shfl_xor(sum, off);
    float a = e / sum;
    float cacc = 0.f;
    for (int j = 0; j < cnt; j++) {
      float aj = __shfl(a, j);
      cacc += aj * vs[j][lane];
    }
    int l = qidx[qi];
    int b = bh >> 3, h = bh & 7;
    ctx[((size_t)(b * Ll + l)) * 512 + h * 64 + lane] = cacc;
  }
}

// ---------------------------------------------------------------------------
// T[h,dk,n] = sum_r U[h,dk,r] * V[h,r,n]
// ---------------------------------------------------------------------------
__global__ __launch_bounds__(256) void uv_kernel(
    const float* __restrict__ U, const float* __restrict__ V, float* __restrict__ T)
{
  int idx = blockIdx.x * 256 + threadIdx.x;     // 8*64*512
  int n = idx & 511, dk = (idx >> 9) & 63, h = idx >> 15;
  float acc = 0.f;
  #pragma unroll
  for (int r = 0; r < 32; r++)
    acc += U[((size_t)h * 64 + dk) * 32 + r] * V[((size_t)h * 32 + r) * 512 + n];
  T[idx] = acc;
}

// ---------------------------------------------------------------------------
// Mf[h*64+dk, n] = sum_c T[h,dk,c] * Wo[h*512+c, n]
// ---------------------------------------------------------------------------
__global__ __launch_bounds__(256) void m_kernel(
    const float* __restrict__ T, const float* __restrict__ Wo, float* __restrict__ Mf)
{
  int idx = blockIdx.x * 256 + threadIdx.x;     // 512*512
  int n = idx & 511, row = idx >> 9;
  int h = row >> 6;
  float acc = 0.f;
  for (int c = 0; c < 512; c++)
    acc += T[(size_t)row * 512 + c] * Wo[((size_t)h * 512 + c) * 512 + n];
  Mf[idx] = acc;
}

// ---------------------------------------------------------------------------
// OUT(4096x512) = CTX @ Mf + bo
// ---------------------------------------------------------------------------
__global__ __launch_bounds__(256) void out_gemm(
    const float* __restrict__ A, const float* __restrict__ Bm,
    const float* __restrict__ bias, float* __restrict__ C)
{
  __shared__ float As[16][132];
  __shared__ float Bs[16][68];
  const int tid = threadIdx.x;
  const int m0 = blockIdx.y * 128, n0 = blockIdx.x * 64;
  const int tx = tid & 15, ty = tid >> 4;
  float acc[8][4] = {};
  for (int k0 = 0; k0 < 512; k0 += 16) {
    #pragma unroll
    for (int i = 0; i < 2; i++) {
      int f = tid * 2 + i;
      int row = f >> 2, colg = (f & 3) << 2;
      float4 a = *(const float4*)&A[(size_t)(m0 + row) * 512 + k0 + colg];
      As[colg+0][row]=a.x; As[colg+1][row]=a.y; As[colg+2][row]=a.z; As[colg+3][row]=a.w;
    }
    {
      int row = tid >> 4, colg = (tid & 15) << 2;
      *(float4*)&Bs[row][colg] = *(const float4*)&Bm[(size_t)(k0+row)*512 + n0 + colg];
    }
    __syncthreads();
    #pragma unroll
    for (int kk = 0; kk < 16; kk++) {
      float4 a0 = *(const float4*)&As[kk][ty*8];
      float4 a1 = *(const float4*)&As[kk][ty*8+4];
      float4 b0 = *(const float4*)&Bs[kk][tx*4];
      float av[8] = {a0.x,a0.y,a0.z,a0.w,a1.x,a1.y,a1.z,a1.w};
      float bw[4] = {b0.x,b0.y,b0.z,b0.w};
      #pragma unroll
      for (int i=0;i<8;i++)
        #pragma unroll
        for (int j=0;j<4;j++) acc[i][j] += av[i]*bw[j];
    }
    __syncthreads();
  }
  #pragma unroll
  for (int i=0;i<8;i++) {
    int m = m0 + ty*8 + i;
    #pragma unroll
    for (int j=0;j<4;j++) {
      int n = n0 + tx*4 + j;
      C[(size_t)m * 512 + n] = acc[i][j] + bias[n];
    }
  }
}

// ---------------------------------------------------------------------------
extern "C" void kernel_launch(void* const* d_in, const int* in_sizes, int n_in,
                              void* d_out, int out_size, void* d_ws, size_t ws_size,
                              hipStream_t stream)
{
  const float* query = (const float*)d_in[0];
  const float* key   = (const float*)d_in[1];
  const float* value = (const float*)d_in[2];
  const float* Wq = (const float*)d_in[3];
  const float* bq = (const float*)d_in[4];
  const float* Wk = (const float*)d_in[5];
  const float* bk = (const float*)d_in[6];
  const float* Wv = (const float*)d_in[7];
  const float* bv = (const float*)d_in[8];
  const float* U  = (const float*)d_in[9];
  const float* V  = (const float*)d_in[10];
  const float* rv = (const float*)d_in[11];
  const float* Wo = (const float*)d_in[12];
  const float* bo = (const float*)d_in[13];
  float* out = (float*)d_out;

  float* ws = (float*)d_ws;
  const size_t NQKV = (size_t)Bb * Hh * Ll * DKq;    // 2,097,152
  float* qb   = ws;
  float* kb   = qb + NQKV;
  float* vb   = kb + NQKV;
  float* ctx  = vb + NQKV;                            // (b,l, h*64+d) = 4096x512
  float* T    = ctx + NQKV;                           // 8*64*512
  float* Mf   = T + (size_t)Hh * DKq * 512;           // 512*512
  int* qhash  = (int*)(Mf + 512 * 512);               // 32768
  int* khash  = qhash + Bb * Hh * Ll;
  int* kcand  = khash + Bb * Hh * Ll;                 // 256*64
  int* kcount = kcand + Bb * Hh * NBUCK * KMAX;       // 256
  int* qoff   = kcount + Bb * Hh * NBUCK;             // 16*17
  int* qlist  = qoff + Bb * Hh * (NBUCK + 1);         // 32768

  // 1. projections (q,k,v) -> (b,h,l,dk)
  proj_kernel<<<dim3(8, 32, 3), 256, 0, stream>>>(query, key, value,
                                                  Wq, Wk, Wv, bq, bk, bv,
                                                  qb, kb, vb);
  // 2. hashes
  hash_kernel<<<(2 * Bb * Hh * Ll * 64) / 256, 256, 0, stream>>>(qb, kb, rv, qhash, khash);
  // 3. candidate key lists per bucket
  kcand_kernel<<<Bb * Hh * NBUCK, 64, 0, stream>>>(khash, kcand, kcount);
  // 4. query grouping per bucket
  qlist_kernel<<<Bb * Hh, 256, 0, stream>>>(qhash, qoff, qlist);
  // 5. attention -> ctx (b,l,512)
  attn_kernel<<<Bb * Hh * NBUCK * 32, 256, 0, stream>>>(qb, kb, vb, qoff, qlist,
                                                        kcand, kcount, ctx);
  // 6. fused output matrix M = U@V@Wo_slice
  uv_kernel<<<(Hh * DKq * 512) / 256, 256, 0, stream>>>(U, V, T);
  m_kernel<<<(512 * 512) / 256, 256, 0, stream>>>(T, Wo, Mf);
  // 7. out = ctx @ Mf + bo
  out_gemm<<<dim3(8, 32), 256, 0, stream>>>(ctx, Mf, bo, out);
}

// Round 2
// 408.677 us; speedup vs baseline: 1.0618x; 1.0618x over previous
//
#include <hip/hip_runtime.h>
#include <math.h>

// Problem constants (from reference)
#define Bb 2
#define Ll 2048
#define Dd 512
#define Hh 8
#define DKq 64
#define NBUCK 16
#define KMAX 64
// M = B*L = 4096 rows for all big GEMMs, K=N=512

// ---------------------------------------------------------------------------
// Projection GEMM: X(4096x512) @ W(512x512) + b, output scattered to
// (b, h, l, dk) layout for q/k/v.  BM=128 BN=64 BK=16, 256 thr, 8x4 microtile.
// UNCHANGED from round 1 (q/k accumulation order is sign-critical for LSH).
// ---------------------------------------------------------------------------
__global__ __launch_bounds__(256) void proj_kernel(
    const float* __restrict__ Xq, const float* __restrict__ Xk, const float* __restrict__ Xv,
    const float* __restrict__ Wq, const float* __restrict__ Wk, const float* __restrict__ Wv,
    const float* __restrict__ bq, const float* __restrict__ bk, const float* __restrict__ bv,
    float* __restrict__ qb, float* __restrict__ kb, float* __restrict__ vb)
{
  const float *X, *W, *bias; float* dst;
  if (blockIdx.z == 0)      { X=Xq; W=Wq; bias=bq; dst=qb; }
  else if (blockIdx.z == 1) { X=Xk; W=Wk; bias=bk; dst=kb; }
  else                      { X=Xv; W=Wv; bias=bv; dst=vb; }
  __shared__ float As[16][132];
  __shared__ float Bs[16][68];
  const int tid = threadIdx.x;
  const int m0 = blockIdx.y * 128;
  const int head = blockIdx.x;
  const int n0 = head * 64;
  const int tx = tid & 15, ty = tid >> 4;
  float acc[8][4] = {};
  for (int k0 = 0; k0 < 512; k0 += 16) {
    #pragma unroll
    for (int i = 0; i < 2; i++) {
      int f = tid * 2 + i;
      int row = f >> 2, colg = (f & 3) << 2;
      float4 a = *(const float4*)&X[(size_t)(m0 + row) * 512 + k0 + colg];
      As[colg+0][row]=a.x; As[colg+1][row]=a.y; As[colg+2][row]=a.z; As[colg+3][row]=a.w;
    }
    {
      int row = tid >> 4, colg = (tid & 15) << 2;
      *(float4*)&Bs[row][colg] = *(const float4*)&W[(size_t)(k0+row)*512 + n0 + colg];
    }
    __syncthreads();
    #pragma unroll
    for (int kk = 0; kk < 16; kk++) {
      float4 a0 = *(const float4*)&As[kk][ty*8];
      float4 a1 = *(const float4*)&As[kk][ty*8+4];
      float4 b0 = *(const float4*)&Bs[kk][tx*4];
      float av[8] = {a0.x,a0.y,a0.z,a0.w,a1.x,a1.y,a1.z,a1.w};
      float bw[4] = {b0.x,b0.y,b0.z,b0.w};
      #pragma unroll
      for (int i=0;i<8;i++)
        #pragma unroll
        for (int j=0;j<4;j++) acc[i][j] += av[i]*bw[j];
    }
    __syncthreads();
  }
  #pragma unroll
  for (int i=0;i<8;i++) {
    int m = m0 + ty*8 + i;
    int b = m >> 11, l = m & 2047;
    float* drow = &dst[(((size_t)b*Hh + head)*Ll + l)*DKq];
    #pragma unroll
    for (int j=0;j<4;j++) {
      int d = tx*4+j;
      drow[d] = acc[i][j] + bias[n0 + d];
    }
  }
}

// ---------------------------------------------------------------------------
// LSH hash (unchanged)
// ---------------------------------------------------------------------------
__global__ __launch_bounds__(256) void hash_kernel(
    const float* __restrict__ qb, const float* __restrict__ kb,
    const float* __restrict__ rv, int* __restrict__ qhash, int* __restrict__ khash)
{
  int gwave = (blockIdx.x * blockDim.x + threadIdx.x) >> 6;
  int lane = threadIdx.x & 63;
  const int NR = Bb * Hh * Ll;
  if (gwave >= 2 * NR) return;
  int isK = gwave >= NR;
  int row = isK ? gwave - NR : gwave;
  int h = (row >> 11) & 7;
  const float* src = isK ? kb : qb;
  float x = src[(size_t)row * DKq + lane];
  float r = rv[h * DKq + lane];
  float v = (x > 0.0f) ? r : 0.0f;
  #pragma unroll
  for (int off = 32; off; off >>= 1) v += __shfl_xor(v, off);
  if (lane == 0) {
    float fb = floorf(v * 0.125f);
    int ib = (int)fb;
    int bucket = ib & 15;
    (isK ? khash : qhash)[row] = bucket;
  }
}

// ---------------------------------------------------------------------------
// First <=64 ascending key indices per (b,h,bucket) (unchanged)
// ---------------------------------------------------------------------------
__global__ __launch_bounds__(64) void kcand_kernel(
    const int* __restrict__ khash, int* __restrict__ kcand, int* __restrict__ kcount)
{
  int bh = blockIdx.x >> 4;
  int bucket = blockIdx.x & 15;
  int lane = threadIdx.x;
  const int* kh = &khash[bh * Ll];
  int* cl = &kcand[(size_t)blockIdx.x * KMAX];
  int total = 0;
  for (int c0 = 0; c0 < Ll && total < KMAX; c0 += 64) {
    int hv = kh[c0 + lane];
    unsigned long long m = __ballot(hv == bucket);
    int pre = __popcll(m & ((1ULL << lane) - 1ULL));
    if (hv == bucket && total + pre < KMAX) cl[total + pre] = c0 + lane;
    total += __popcll(m);
  }
  if (lane == 0) kcount[blockIdx.x] = total < KMAX ? total : KMAX;
}

// ---------------------------------------------------------------------------
// Group queries by bucket per (b,h) (unchanged)
// ---------------------------------------------------------------------------
__global__ __launch_bounds__(256) void qlist_kernel(
    const int* __restrict__ qhash, int* __restrict__ qoff, int* __restrict__ qlist)
{
  int bh = blockIdx.x;
  __shared__ int cnt[NBUCK], cur[NBUCK], off[NBUCK + 1];
  if (threadIdx.x < NBUCK) cnt[threadIdx.x] = 0;
  __syncthreads();
  const int* qh = &qhash[bh * Ll];
  for (int l = threadIdx.x; l < Ll; l += 256) atomicAdd(&cnt[qh[l]], 1);
  __syncthreads();
  if (threadIdx.x == 0) {
    int s = 0;
    for (int i = 0; i < NBUCK; i++) { off[i] = s; cur[i] = s; s += cnt[i]; }
    off[NBUCK] = s;
  }
  __syncthreads();
  if (threadIdx.x < NBUCK + 1) qoff[bh * (NBUCK + 1) + threadIdx.x] = off[threadIdx.x];
  for (int l = threadIdx.x; l < Ll; l += 256) {
    int p = atomicAdd(&cur[qh[l]], 1);
    qlist[bh * Ll + p] = l;
  }
}

// ---------------------------------------------------------------------------
// Attention, GEMM-ified.  Block = (b,h,bucket,chunk).  Two 64x64x64 f32
// GEMMs (QK^T and P@V) with 4x4 register microtiles on a 16x16 thread grid.
// Row softmax via __shfl_xor inside 16-lane groups.  Q LDS reused for P.
// ---------------------------------------------------------------------------
__global__ __launch_bounds__(256) void attn_kernel(
    const float* __restrict__ qb, const float* __restrict__ kb, const float* __restrict__ vb,
    const int* __restrict__ qoff, const int* __restrict__ qlist,
    const int* __restrict__ kcand, const int* __restrict__ kcount,
    float* __restrict__ ctx)
{
  int gb = blockIdx.x;
  int chunk = gb & 31;
  int bucket = (gb >> 5) & 15;
  int bh = gb >> 9;
  int o0 = qoff[bh * 17 + bucket], o1 = qoff[bh * 17 + bucket + 1];
  int nq = o1 - o0 - chunk * 64;
  if (nq <= 0) return;
  if (nq > 64) nq = 64;
  int cnt = kcount[bh * 16 + bucket];
  if (cnt == 0) return;   // ref would be NaN; absent in data (verified round 1)

  __shared__ float qs[64][68];   // later reused to hold P
  __shared__ float ks[64][68];
  __shared__ float vs[64][68];
  __shared__ int cidx[64], qidx[64];
  const int tid = threadIdx.x;
  if (tid < 64) {
    cidx[tid] = (tid < cnt) ? kcand[((size_t)bh * 16 + bucket) * KMAX + tid] : 0;
    qidx[tid] = (tid < nq) ? qlist[bh * Ll + o0 + chunk * 64 + tid] : 0;
  }
  __syncthreads();
  const float* kbh = &kb[(size_t)bh * Ll * DKq];
  const float* vbh = &vb[(size_t)bh * Ll * DKq];
  const float* qbh = &qb[(size_t)bh * Ll * DKq];
  for (int idx = tid; idx < 64 * 64; idx += 256) {
    int r = idx >> 6, d = idx & 63;
    ks[r][d] = (r < cnt) ? kbh[(size_t)cidx[r] * DKq + d] : 0.0f;
    vs[r][d] = (r < cnt) ? vbh[(size_t)cidx[r] * DKq + d] : 0.0f;
    qs[r][d] = (r < nq)  ? qbh[(size_t)qidx[r] * DKq + d] : 0.0f;
  }
  __syncthreads();

  const int tx = tid & 15, ty = tid >> 4;
  // ---- Phase A: S[r][c] = (Q K^T)/8, rows 4ty+i, cols tx+16j ----
  float acc[4][4] = {};
  #pragma unroll
  for (int dq = 0; dq < 16; dq++) {
    float4 av[4], bv[4];
    #pragma unroll
    for (int i = 0; i < 4; i++) av[i] = *(const float4*)&qs[4*ty + i][4*dq];
    #pragma unroll
    for (int j = 0; j < 4; j++) bv[j] = *(const float4*)&ks[tx + 16*j][4*dq];
    #pragma unroll
    for (int i = 0; i < 4; i++)
      #pragma unroll
      for (int j = 0; j < 4; j++)
        acc[i][j] += av[i].x*bv[j].x + av[i].y*bv[j].y + av[i].z*bv[j].z + av[i].w*bv[j].w;
  }
  // ---- softmax over rows (16 lanes per row hold 4 cols each) ----
  float p[4][4];
  #pragma unroll
  for (int i = 0; i < 4; i++) {
    float s[4];
    float m = -INFINITY;
    #pragma unroll
    for (int j = 0; j < 4; j++) {
      int c = tx + 16*j;
      s[j] = (c < cnt) ? acc[i][j] * 0.125f : -INFINITY;
      m = fmaxf(m, s[j]);
    }
    #pragma unroll
    for (int off = 1; off < 16; off <<= 1) m = fmaxf(m, __shfl_xor(m, off));
    float sum = 0.0f;
    #pragma unroll
    for (int j = 0; j < 4; j++) { s[j] = expf(s[j] - m); sum += s[j]; }
    #pragma unroll
    for (int off = 1; off < 16; off <<= 1) sum += __shfl_xor(sum, off);
    float inv = 1.0f / sum;
    #pragma unroll
    for (int j = 0; j < 4; j++) p[i][j] = s[j] * inv;
  }
  __syncthreads();            // all Phase-A qs reads done
  #pragma unroll
  for (int i = 0; i < 4; i++)
    #pragma unroll
    for (int j = 0; j < 4; j++)
      qs[4*ty + i][tx + 16*j] = p[i][j];     // qs now holds P
  __syncthreads();

  // ---- Phase C: CTX[r][dv] = P @ V, rows 4ty+i, cols 4tx+jj ----
  float cacc[4][4] = {};
  #pragma unroll
  for (int cq = 0; cq < 16; cq++) {
    float4 pv[4], vv[4];
    #pragma unroll
    for (int i = 0; i < 4; i++) pv[i] = *(const float4*)&qs[4*ty + i][4*cq];
    #pragma unroll
    for (int cc = 0; cc < 4; cc++) vv[cc] = *(const float4*)&vs[4*cq + cc][4*tx];
    #pragma unroll
    for (int i = 0; i < 4; i++) {
      cacc[i][0] += pv[i].x*vv[0].x + pv[i].y*vv[1].x + pv[i].z*vv[2].x + pv[i].w*vv[3].x;
      cacc[i][1] += pv[i].x*vv[0].y + pv[i].y*vv[1].y + pv[i].z*vv[2].y + pv[i].w*vv[3].y;
      cacc[i][2] += pv[i].x*vv[0].z + pv[i].y*vv[1].z + pv[i].z*vv[2].z + pv[i].w*vv[3].z;
      cacc[i][3] += pv[i].x*vv[0].w + pv[i].y*vv[1].w + pv[i].z*vv[2].w + pv[i].w*vv[3].w;
    }
  }
  int b = bh >> 3, h = bh & 7;
  #pragma unroll
  for (int i = 0; i < 4; i++) {
    int r = 4*ty + i;
    if (r < nq) {
      int l = qidx[r];
      float4 o = make_float4(cacc[i][0], cacc[i][1], cacc[i][2], cacc[i][3]);
      *(float4*)&ctx[((size_t)(b * Ll + l)) * 512 + h * 64 + 4*tx] = o;
    }
  }
}

// ---------------------------------------------------------------------------
// T[h,dk,n] = sum_r U[h,dk,r] * V[h,r,n]  (unchanged)
// ---------------------------------------------------------------------------
__global__ __launch_bounds__(256) void uv_kernel(
    const float* __restrict__ U, const float* __restrict__ V, float* __restrict__ T)
{
  int idx = blockIdx.x * 256 + threadIdx.x;
  int n = idx & 511, dk = (idx >> 9) & 63, h = idx >> 15;
  float acc = 0.f;
  #pragma unroll
  for (int r = 0; r < 32; r++)
    acc += U[((size_t)h * 64 + dk) * 32 + r] * V[((size_t)h * 32 + r) * 512 + n];
  T[idx] = acc;
}

// ---------------------------------------------------------------------------
// Mf[h*64+dk, n] = sum_c T[h,dk,c] * Wo[h*512+c, n]  (unchanged)
// ---------------------------------------------------------------------------
__global__ __launch_bounds__(256) void m_kernel(
    const float* __restrict__ T, const float* __restrict__ Wo, float* __restrict__ Mf)
{
  int idx = blockIdx.x * 256 + threadIdx.x;
  int n = idx & 511, row = idx >> 9;
  int h = row >> 6;
  float acc = 0.f;
  for (int c = 0; c < 512; c++)
    acc += T[(size_t)row * 512 + c] * Wo[((size_t)h * 512 + c) * 512 + n];
  Mf[idx] = acc;
}

// ---------------------------------------------------------------------------
// OUT(4096x512) = CTX @ Mf + bo  (unchanged)
// ---------------------------------------------------------------------------
__global__ __launch_bounds__(256) void out_gemm(
    const float* __restrict__ A, const float* __restrict__ Bm,
    const float* __restrict__ bias, float* __restrict__ C)
{
  __shared__ float As[16][132];
  __shared__ float Bs[16][68];
  const int tid = threadIdx.x;
  const int m0 = blockIdx.y * 128, n0 = blockIdx.x * 64;
  const int tx = tid & 15, ty = tid >> 4;
  float acc[8][4] = {};
  for (int k0 = 0; k0 < 512; k0 += 16) {
    #pragma unroll
    for (int i = 0; i < 2; i++) {
      int f = tid * 2 + i;
      int row = f >> 2, colg = (f & 3) << 2;
      float4 a = *(const float4*)&A[(size_t)(m0 + row) * 512 + k0 + colg];
      As[colg+0][row]=a.x; As[colg+1][row]=a.y; As[colg+2][row]=a.z; As[colg+3][row]=a.w;
    }
    {
      int row = tid >> 4, colg = (tid & 15) << 2;
      *(float4*)&Bs[row][colg] = *(const float4*)&Bm[(size_t)(k0+row)*512 + n0 + colg];
    }
    __syncthreads();
    #pragma unroll
    for (int kk = 0; kk < 16; kk++) {
      float4 a0 = *(const float4*)&As[kk][ty*8];
      float4 a1 = *(const float4*)&As[kk][ty*8+4];
      float4 b0 = *(const float4*)&Bs[kk][tx*4];
      float av[8] = {a0.x,a0.y,a0.z,a0.w,a1.x,a1.y,a1.z,a1.w};
      float bw[4] = {b0.x,b0.y,b0.z,b0.w};
      #pragma unroll
      for (int i=0;i<8;i++)
        #pragma unroll
        for (int j=0;j<4;j++) acc[i][j] += av[i]*bw[j];
    }
    __syncthreads();
  }
  #pragma unroll
  for (int i=0;i<8;i++) {
    int m = m0 + ty*8 + i;
    #pragma unroll
    for (int j=0;j<4;j++) {
      int n = n0 + tx*4 + j;
      C[(size_t)m * 512 + n] = acc[i][j] + bias[n];
    }
  }
}

// ---------------------------------------------------------------------------
extern "C" void kernel_launch(void* const* d_in, const int* in_sizes, int n_in,
                              void* d_out, int out_size, void* d_ws, size_t ws_size,
                              hipStream_t stream)
{
  const float* query = (const float*)d_in[0];
  const float* key   = (const float*)d_in[1];
  const float* value = (const float*)d_in[2];
  const float* Wq = (const float*)d_in[3];
  const float* bq = (const float*)d_in[4];
  const float* Wk = (const float*)d_in[5];
  const float* bk = (const float*)d_in[6];
  const float* Wv = (const float*)d_in[7];
  const float* bv = (const float*)d_in[8];
  const float* U  = (const float*)d_in[9];
  const float* V  = (const float*)d_in[10];
  const float* rv = (const float*)d_in[11];
  const float* Wo = (const float*)d_in[12];
  const float* bo = (const float*)d_in[13];
  float* out = (float*)d_out;

  float* ws = (float*)d_ws;
  const size_t NQKV = (size_t)Bb * Hh * Ll * DKq;
  float* qb   = ws;
  float* kb   = qb + NQKV;
  float* vb   = kb + NQKV;
  float* ctx  = vb + NQKV;
  float* T    = ctx + NQKV;
  float* Mf   = T + (size_t)Hh * DKq * 512;
  int* qhash  = (int*)(Mf + 512 * 512);
  int* khash  = qhash + Bb * Hh * Ll;
  int* kcand  = khash + Bb * Hh * Ll;
  int* kcount = kcand + Bb * Hh * NBUCK * KMAX;
  int* qoff   = kcount + Bb * Hh * NBUCK;
  int* qlist  = qoff + Bb * Hh * (NBUCK + 1);

  proj_kernel<<<dim3(8, 32, 3), 256, 0, stream>>>(query, key, value,
                                                  Wq, Wk, Wv, bq, bk, bv,
                                                  qb, kb, vb);
  hash_kernel<<<(2 * Bb * Hh * Ll * 64) / 256, 256, 0, stream>>>(qb, kb, rv, qhash, khash);
  kcand_kernel<<<Bb * Hh * NBUCK, 64, 0, stream>>>(khash, kcand, kcount);
  qlist_kernel<<<Bb * Hh, 256, 0, stream>>>(qhash, qoff, qlist);
  attn_kernel<<<Bb * Hh * NBUCK * 32, 256, 0, stream>>>(qb, kb, vb, qoff, qlist,
                                                        kcand, kcount, ctx);
  uv_kernel<<<(Hh * DKq * 512) / 256, 256, 0, stream>>>(U, V, T);
  m_kernel<<<(512 * 512) / 256, 256, 0, stream>>>(T, Wo, Mf);
  out_gemm<<<dim3(8, 32), 256, 0, stream>>>(ctx, Mf, bo, out);
}